// Round 6
// baseline (495.154 us; speedup 1.0000x reference)
//
#include <hip/hip_runtime.h>

#define B_  2
#define S_  2048
#define D_  2048
#define H_  16
#define HD_ 128

typedef __bf16 bf16;
typedef __bf16 bf16x4 __attribute__((ext_vector_type(4)));
typedef __bf16 bf16x8 __attribute__((ext_vector_type(8)));
typedef float  f32x4  __attribute__((ext_vector_type(4)));
typedef unsigned int u32x4 __attribute__((ext_vector_type(4)));

// async global->LDS 16B copy: lds dst = wave-uniform base + lane*16
__device__ __forceinline__ void gld_lds16(const void* g, void* l) {
    __builtin_amdgcn_global_load_lds(
        (const __attribute__((address_space(1))) unsigned int*)g,
        (__attribute__((address_space(3))) unsigned int*)l, 16, 0, 0);
}

__device__ __forceinline__ f32x4 mfma16(bf16x8 a, bf16x8 b, f32x4 c) {
    return __builtin_amdgcn_mfma_f32_16x16x32_bf16(a, b, c, 0, 0, 0);
}

// raw barrier with compiler memory fence (does NOT drain vmcnt - that's the point)
#define BAR()  asm volatile("s_barrier" ::: "memory")
// rule-18: sched_barrier(0) right after lgkmcnt(0) so MFMAs can't hoist past the wait
#define WAIT_LGKM0() do { asm volatile("s_waitcnt lgkmcnt(0)" ::: "memory"); \
                          __builtin_amdgcn_sched_barrier(0); } while (0)

// ---------------- fused precast: x -> hi/lo planes, qm/km -> bf16 ----------------
__global__ __launch_bounds__(256)
void precast_all(const float* __restrict__ x, bf16* __restrict__ xh,
                 bf16* __restrict__ xl,
                 const float* __restrict__ qm, bf16* __restrict__ qmb,
                 const float* __restrict__ km, bf16* __restrict__ kmb,
                 const float* __restrict__ swp) {
    int bid = blockIdx.x;
    if (bid < 4096) {
        int i = (bid * 256 + threadIdx.x) * 8;
        float4 a = *(const float4*)(x + i);
        float4 b = *(const float4*)(x + i + 4);
        float av[8] = {a.x, a.y, a.z, a.w, b.x, b.y, b.z, b.w};
        bf16x8 h8, l8;
#pragma unroll
        for (int e = 0; e < 8; e++) {
            bf16 hv = (bf16)av[e];
            h8[e] = hv;
            l8[e] = (bf16)(av[e] - (float)hv);
        }
        *(bf16x8*)(xh + i) = h8;
        *(bf16x8*)(xl + i) = l8;
        return;
    }
    const float sw = swp[0];
    bid -= 4096;
    const float* src = qm; bf16* dst = qmb;
    if (bid >= 2048) { src = km; dst = kmb; bid -= 2048; }
    int i = (bid * 256 + threadIdx.x) * 8;
    float4 a = *(const float4*)(src + i);
    float4 b = *(const float4*)(src + i + 4);
    bf16x8 o;
    o[0] = (bf16)(a.x * sw); o[1] = (bf16)(a.y * sw);
    o[2] = (bf16)(a.z * sw); o[3] = (bf16)(a.w * sw);
    o[4] = (bf16)(b.x * sw); o[5] = (bf16)(b.y * sw);
    o[6] = (bf16)(b.z * sw); o[7] = (bf16)(b.w * sw);
    *(bf16x8*)(dst + i) = o;
}

// ---------------- precast masks: f32 * sw -> bf16 (single mask) ----------------
__global__ __launch_bounds__(256)
void precast_mask(const float* __restrict__ s0, bf16* __restrict__ d0,
                  const float* __restrict__ swp) {
    const float sw = swp[0];
    int i = (blockIdx.x * 256 + threadIdx.x) * 8;
    float4 a = *(const float4*)(s0 + i);
    float4 b = *(const float4*)(s0 + i + 4);
    bf16x8 o;
    o[0] = (bf16)(a.x * sw); o[1] = (bf16)(a.y * sw);
    o[2] = (bf16)(a.z * sw); o[3] = (bf16)(a.w * sw);
    o[4] = (bf16)(b.x * sw); o[5] = (bf16)(b.y * sw);
    o[6] = (bf16)(b.z * sw); o[7] = (bf16)(b.w * sw);
    *(bf16x8*)(d0 + i) = o;
}

// ============ m201-style 256x256 8-phase GEMM (q/k projection only) ============
// 8 waves (2M x 4N), per-wave 128x64 out, BK=64, LDS = 2 buf x 4 halves x 128x64.
// Virtual K = 4096: tiles 0..31 = xh plane, 32..63 = xl plane (B repeats).
// Per 2-K-tile iteration, 8 phases: {quadrant ds_reads | 1 half-tile stage ->
// bar -> lgkm0 -> setprio 16xMFMA -> bar}. Stage slots follow half free-times
// (A halves read p1&p3 / p5&p7; B halves p1&p2 / p5&p6). vmcnt(4) gates at
// phases 4 and 8 only (FIFO: needed halves are exactly 4 loads behind);
// vmcnt(0) in the final iteration. Prologue: buf0 x4 + buf1.B0/B1, vmcnt(4).
__global__ __launch_bounds__(512, 1)
void gemm8x(const bf16* __restrict__ Ah_g, const bf16* __restrict__ Al_g,
            const bf16* __restrict__ Bq, const bf16* __restrict__ Bk,
            const float* __restrict__ hm,
            bf16* __restrict__ o_qh, bf16* __restrict__ o_ql,
            bf16* __restrict__ o_kh, bf16* __restrict__ o_kl,
            int nt) {
    __shared__ bf16 sm[2 * 4 * 128 * 64];        // 128 KiB
    const int t = threadIdx.x;
    const int wave = t >> 6, lane = t & 63;
    const int lrow = lane & 15, quad = lane >> 4;
    const int wr = wave >> 2, wc = wave & 3;     // 2M x 4N wave grid

    // XCD-aware bijective swizzle (256 blocks = 8*32)
    const int gx = gridDim.x;
    const int id0 = blockIdx.y * gx + blockIdx.x;
    const int id = (id0 & 7) * 32 + (id0 >> 3);
    const int m0 = (id / gx) * 256, n0 = (id % gx) * 256;

    const int nsec = n0 & (D_ - 1);
    const bf16* Bg = (n0 >= D_) ? Bk : Bq;

    const int g0 = (quad ^ (lrow & 7)) * 8;      // swizzled k-groups (128B rows)
    const int g1 = ((4 + quad) ^ (lrow & 7)) * 8;

    auto stage_half = [&](int kt, int p, int h) {   // h: 0=A0 1=A1 2=B0 3=B1
        if (kt >= nt) return;
        const bf16* plane = (kt >= 32) ? Al_g : Ah_g;
        const int kc = (kt & 31) * 64;
        bf16* dst = sm + (p * 4 + h) * (128 * 64);
#pragma unroll
        for (int is = 0; is < 2; is++) {
            int rbase = wave * 16 + is * 8;
            int r = rbase + (lane >> 3);
            int gsrc = ((lane & 7) ^ (r & 7)) * 8;   // pre-swizzled source col
            const bf16* g = (h < 2)
                ? plane + (size_t)(m0 + h * 128 + r) * D_ + kc + gsrc
                : Bg + (size_t)(nsec + (h - 2) * 128 + r) * D_ + kc + gsrc;
            gld_lds16(g, dst + rbase * 64);
        }
    };
    auto rdAq = [&](int p, int qm, int i, int ge) -> bf16x8 {
        const bf16* base = sm + (p * 4 + wr) * (128 * 64);
        return *(const bf16x8*)&base[(qm * 64 + i * 16 + lrow) * 64 + ge];
    };
    auto rdBq = [&](int p, int qn, int j, int ge) -> bf16x8 {
        const bf16* base = sm + (p * 4 + 2 + (wc >> 1)) * (128 * 64);
        return *(const bf16x8*)&base[((wc & 1) * 64 + qn * 32 + j * 16 + lrow) * 64 + ge];
    };

    f32x4 acc[8][4];
#pragma unroll
    for (int i = 0; i < 8; i++)
#pragma unroll
        for (int j = 0; j < 4; j++) acc[i][j] = (f32x4){0.f, 0.f, 0.f, 0.f};

    bf16x8 aF[4][2], bQ0[2][2], bQ1[2][2];

    auto quadmm = [&](int qm, int qn, bf16x8 (&a)[4][2], bf16x8 (&b)[2][2]) {
        __builtin_amdgcn_s_setprio(1);
#pragma unroll
        for (int i = 0; i < 4; i++)
#pragma unroll
            for (int j = 0; j < 2; j++) {
                acc[qm * 4 + i][qn * 2 + j] =
                    mfma16(a[i][0], b[j][0], acc[qm * 4 + i][qn * 2 + j]);
                acc[qm * 4 + i][qn * 2 + j] =
                    mfma16(a[i][1], b[j][1], acc[qm * 4 + i][qn * 2 + j]);
            }
        __builtin_amdgcn_s_setprio(0);
    };

    // prologue: buf0 <- tile0 (all 4 halves), buf1 <- tile1 (B halves only;
    // A halves staged at p1/p2 of iteration 0). vmcnt(4) completes buf0.
    stage_half(0, 0, 0); stage_half(0, 0, 1); stage_half(0, 0, 2); stage_half(0, 0, 3);
    stage_half(1, 1, 2); stage_half(1, 1, 3);
    asm volatile("s_waitcnt vmcnt(4)" ::: "memory");
    BAR();

    const int nj = nt >> 1;
    for (int J = 0; J < nj; ++J) {
        const int tq = 2 * J;
        const bool last = (J == nj - 1);

        // ---- p1: buf0 A(qm0)+B(qn0); stage buf1.A0 <- tq+1; quad (0,0)
#pragma unroll
        for (int i = 0; i < 4; i++) { aF[i][0] = rdAq(0, 0, i, g0); aF[i][1] = rdAq(0, 0, i, g1); }
#pragma unroll
        for (int j = 0; j < 2; j++) { bQ0[j][0] = rdBq(0, 0, j, g0); bQ0[j][1] = rdBq(0, 0, j, g1); }
        stage_half(tq + 1, 1, 0);
        BAR(); WAIT_LGKM0();
        quadmm(0, 0, aF, bQ0);
        BAR();
        // ---- p2: B(qn1); stage buf1.A1 <- tq+1; quad (0,1)
#pragma unroll
        for (int j = 0; j < 2; j++) { bQ1[j][0] = rdBq(0, 1, j, g0); bQ1[j][1] = rdBq(0, 1, j, g1); }
        stage_half(tq + 1, 1, 1);
        BAR(); WAIT_LGKM0();
        quadmm(0, 1, aF, bQ1);
        BAR();
        // ---- p3: A(qm1); stage buf0.B0 <- tq+2; quad (1,0)
#pragma unroll
        for (int i = 0; i < 4; i++) { aF[i][0] = rdAq(0, 1, i, g0); aF[i][1] = rdAq(0, 1, i, g1); }
        stage_half(tq + 2, 0, 2);
        BAR(); WAIT_LGKM0();
        quadmm(1, 0, aF, bQ0);
        BAR();
        // ---- p4: stage buf0.B1 <- tq+2; GATE buf1 (tq+1) complete; quad (1,1)
        stage_half(tq + 2, 0, 3);
        if (last) asm volatile("s_waitcnt vmcnt(0)" ::: "memory");
        else      asm volatile("s_waitcnt vmcnt(4)" ::: "memory");
        BAR();
        quadmm(1, 1, aF, bQ1);
        BAR();
        // ---- p5: buf1 A(qm0)+B(qn0); stage buf0.A0 <- tq+2; quad (0,0)
#pragma unroll
        for (int i = 0; i < 4; i++) { aF[i][0] = rdAq(1, 0, i, g0); aF[i][1] = rdAq(1, 0, i, g1); }
#pragma unroll
        for (int j = 0; j < 2; j++) { bQ0[j][0] = rdBq(1, 0, j, g0); bQ0[j][1] = rdBq(1, 0, j, g1); }
        stage_half(tq + 2, 0, 0);
        BAR(); WAIT_LGKM0();
        quadmm(0, 0, aF, bQ0);
        BAR();
        // ---- p6: buf1 B(qn1); stage buf0.A1 <- tq+2; quad (0,1)
#pragma unroll
        for (int j = 0; j < 2; j++) { bQ1[j][0] = rdBq(1, 1, j, g0); bQ1[j][1] = rdBq(1, 1, j, g1); }
        stage_half(tq + 2, 0, 1);
        BAR(); WAIT_LGKM0();
        quadmm(0, 1, aF, bQ1);
        BAR();
        // ---- p7: buf1 A(qm1); stage buf1.B0 <- tq+3; quad (1,0)
#pragma unroll
        for (int i = 0; i < 4; i++) { aF[i][0] = rdAq(1, 1, i, g0); aF[i][1] = rdAq(1, 1, i, g1); }
        stage_half(tq + 3, 1, 2);
        BAR(); WAIT_LGKM0();
        quadmm(1, 0, aF, bQ0);
        BAR();
        // ---- p8: stage buf1.B1 <- tq+3; GATE buf0 (tq+2) complete; quad (1,1)
        stage_half(tq + 3, 1, 3);
        if (last) asm volatile("s_waitcnt vmcnt(0)" ::: "memory");
        else      asm volatile("s_waitcnt vmcnt(4)" ::: "memory");
        BAR();
        quadmm(1, 1, aF, bQ1);
        BAR();
    }

    // epilogue: *hm, hi/lo split scatter (q or k section)
    const bool isq = (n0 < D_);
    bf16* oh = isq ? o_qh : o_kh;
    bf16* ol = isq ? o_ql : o_kl;
#pragma unroll
    for (int j = 0; j < 4; j++) {
        int nb = nsec + wc * 64 + j * 16;
        int h = nb >> 7;
        float hv = hm[h];
#pragma unroll
        for (int i = 0; i < 8; i++) {
            int mB = m0 + wr * 128 + i * 16 + quad * 4;
            int bb = mB >> 11, s = mB & (S_ - 1);
            size_t idx0 = (((size_t)bb * H_ + h) * S_ + s) * HD_ + (nb & 127) + lrow;
#pragma unroll
            for (int r = 0; r < 4; r++) {
                float v = acc[i][j][r] * hv;
                bf16 hvv = (bf16)v;
                bf16 lvv = (bf16)(v - (float)hvv);
                oh[idx0 + (size_t)r * HD_] = hvv;
                ol[idx0 + (size_t)r * HD_] = lvv;
            }
        }
    }
}

// =================== 2-phase double-buffered GEMM (v / out proj) =======
// round-5 relaxed structure (passing). MODE 1: v proj + V^T epilogue.
// MODE 2: out proj, f32 epilogue.
template<int BM, int BN, int MODE>
__global__ __launch_bounds__(256, 2)
void gemm2p(const bf16* __restrict__ Ah_g, const bf16* __restrict__ Al_g,
            const bf16* __restrict__ Bq, const bf16* __restrict__ Bk,
            const float* __restrict__ hm,
            bf16* __restrict__ o_qh, bf16* __restrict__ o_ql,
            bf16* __restrict__ o_kh, bf16* __restrict__ o_kl,
            bf16* __restrict__ o_vt, float* __restrict__ o_f32,
            int nt) {
    constexpr int IM = BM / 2 / 16;
    constexpr int JN = BN / 2 / 16;
    constexpr int IH = IM / 2;
    constexpr int ISSA = BM / 64;
    constexpr int ISSB = BN / 64;
    constexpr int BUFE = (BM + BN) * 32;
    constexpr int SMELEMS = (MODE == 1 && BN * (BM + 8) > 2 * BUFE)
                                ? BN * (BM + 8) : 2 * BUFE;
    __shared__ bf16 sm[SMELEMS];

    const int t = threadIdx.x;
    const int wave = t >> 6, lane = t & 63;
    const int lrow = lane & 15, quad = lane >> 4;
    const int wr = wave >> 1, wc = wave & 1;

    const int gx = gridDim.x;
    const int id0 = blockIdx.y * gx + blockIdx.x;
    const int nwg = gx * gridDim.y;
    const int id = (id0 & 7) * (nwg >> 3) + (id0 >> 3);
    const int m0 = (id / gx) * BM, n0 = (id % gx) * BN;

    const int nsec = (MODE == 0) ? (n0 & (D_ - 1)) : n0;
    const bf16* Bg = (MODE == 0 && n0 >= D_) ? Bk : Bq;

    const int arow = wr * (BM / 2) + lrow;
    const int brow = wc * (BN / 2) + lrow;
    const int gsw = (quad ^ ((lrow >> 1) & 3)) * 8;

    const int srr = lane >> 2, spg = lane & 3;
    const int ssw = (spg ^ ((srr >> 1) & 3)) * 8;

    auto stage_A = [&](int kt, int pbuf) {
        const bf16* As = (MODE == 0 && kt >= 64) ? Al_g : Ah_g;
        const int kc = ((MODE == 0) ? (kt & 63) : kt) * 32;
        bf16* buf = sm + pbuf * BUFE;
#pragma unroll
        for (int pp = 0; pp < ISSA; pp++) {
            int r0 = wave * (BM / 4) + pp * 16;
            gld_lds16(As + (size_t)(m0 + r0 + srr) * D_ + kc + ssw,
                      buf + r0 * 32);
        }
    };
    auto stage_B = [&](int kt, int pbuf) {
        const int kc = ((MODE == 0) ? (kt & 63) : kt) * 32;
        bf16* buf = sm + pbuf * BUFE + BM * 32;
#pragma unroll
        for (int pp = 0; pp < ISSB; pp++) {
            int r0 = wave * (BN / 4) + pp * 16;
            gld_lds16(Bg + (size_t)(nsec + r0 + srr) * D_ + kc + ssw,
                      buf + r0 * 32);
        }
    };

    f32x4 acc[IM][JN];
#pragma unroll
    for (int i = 0; i < IM; i++)
#pragma unroll
        for (int j = 0; j < JN; j++) acc[i][j] = (f32x4){0.f, 0.f, 0.f, 0.f};

    stage_A(0, 0); stage_B(0, 0); stage_B(1, 1);

    int p = 0;
    for (int kt = 0; kt < nt; ++kt) {
        if (kt < nt - 1) asm volatile("s_waitcnt vmcnt(2)" ::: "memory");
        else             asm volatile("s_waitcnt vmcnt(0)" ::: "memory");
        BAR();
        if (kt + 1 < nt) stage_A(kt + 1, p ^ 1);

        const bf16* Ab = sm + p * BUFE;
        const bf16* Bb = Ab + BM * 32;
        bf16x8 a[IH], b[JN];

#pragma unroll
        for (int j = 0; j < JN; j++)
            b[j] = *(const bf16x8*)&Bb[(brow + j * 16) * 32 + gsw];
#pragma unroll
        for (int i = 0; i < IH; i++)
            a[i] = *(const bf16x8*)&Ab[(arow + i * 16) * 32 + gsw];
        __builtin_amdgcn_s_setprio(1);
#pragma unroll
        for (int i = 0; i < IH; i++)
#pragma unroll
            for (int j = 0; j < JN; j++)
                acc[i][j] = mfma16(a[i], b[j], acc[i][j]);
        __builtin_amdgcn_s_setprio(0);
        BAR();

        if (kt + 2 < nt) stage_B(kt + 2, p);

#pragma unroll
        for (int i = 0; i < IH; i++)
            a[i] = *(const bf16x8*)&Ab[(arow + (IH + i) * 16) * 32 + gsw];
        __builtin_amdgcn_s_setprio(1);
#pragma unroll
        for (int i = 0; i < IH; i++)
#pragma unroll
            for (int j = 0; j < JN; j++)
                acc[IH + i][j] = mfma16(a[i], b[j], acc[IH + i][j]);
        __builtin_amdgcn_s_setprio(0);
        p ^= 1;
    }

    if constexpr (MODE == 0) {
        const bool isq = (n0 < D_);
        bf16* oh = isq ? o_qh : o_kh;
        bf16* ol = isq ? o_ql : o_kl;
#pragma unroll
        for (int j = 0; j < JN; j++) {
            int nb = nsec + wc * (BN / 2) + j * 16;
            int h = nb >> 7;
            float hv = hm[h];
#pragma unroll
            for (int i = 0; i < IM; i++) {
                int mB = m0 + wr * (BM / 2) + i * 16 + quad * 4;
                int bb = mB >> 11, s = mB & (S_ - 1);
                size_t idx0 = (((size_t)bb * H_ + h) * S_ + s) * HD_ + (nb & 127) + lrow;
#pragma unroll
                for (int r = 0; r < 4; r++) {
                    float v = acc[i][j][r] * hv;
                    bf16 hvv = (bf16)v;
                    bf16 lvv = (bf16)(v - (float)hvv);
                    oh[idx0 + (size_t)r * HD_] = hvv;
                    ol[idx0 + (size_t)r * HD_] = lvv;
                }
            }
        }
    }
    if constexpr (MODE == 1) {
        __syncthreads();
        bf16* tr = sm;
#pragma unroll
        for (int j = 0; j < JN; j++) {
            int nl = wc * (BN / 2) + j * 16 + lrow;
            float hv = hm[(n0 + nl) >> 7];
#pragma unroll
            for (int i = 0; i < IM; i++) {
                int ml = wr * (BM / 2) + i * 16 + quad * 4;
                bf16x4 pk;
#pragma unroll
                for (int r = 0; r < 4; r++) pk[r] = (bf16)(acc[i][j][r] * hv);
                *(bf16x4*)&tr[nl * 136 + ml] = pk;
            }
        }
        __syncthreads();
        const int bI = m0 >> 11;
        const int s0 = m0 & (S_ - 1);
#pragma unroll
        for (int w = 0; w < 8; w++) {
            int nrow = w * 16 + (t >> 4);
            int c = t & 15;
            bf16x8 vv = *(const bf16x8*)&tr[nrow * 136 + c * 8];
            int ng = n0 + nrow;
            int h = ng >> 7, hd = ng & 127;
            *(bf16x8*)&o_vt[((size_t)(bI * H_ + h) * HD_ + hd) * S_ + s0 + c * 8] = vv;
        }
    }
    if constexpr (MODE == 2) {
#pragma unroll
        for (int j = 0; j < JN; j++) {
            int n = n0 + wc * (BN / 2) + j * 16 + lrow;
#pragma unroll
            for (int i = 0; i < IM; i++) {
                int mB = m0 + wr * (BM / 2) + i * 16 + quad * 4;
#pragma unroll
                for (int r = 0; r < 4; r++)
                    o_f32[(size_t)(mB + r) * D_ + n] = acc[i][j][r];
            }
        }
    }
}

// =================== causal flash attention (unchanged, round-5 passing) =======
#define SPLD 72

__global__ __launch_bounds__(256, 2)
void attn_kernel(const bf16* __restrict__ qh_, const bf16* __restrict__ ql_,
                 const bf16* __restrict__ kh_, const bf16* __restrict__ kl_,
                 const bf16* __restrict__ vt_, const float* __restrict__ am,
                 bf16* __restrict__ outp) {
    const int id = blockIdx.x;
    const int xcd = id & 7, slot = id >> 3;
    const int bh = xcd * 4 + (slot & 3);
    const int qblk = 31 - (slot >> 2);
    const int b = bh >> 4, h = bh & 15;
    const int i0 = qblk * 64;
    const int t = threadIdx.x, wave = t >> 6, lane = t & 63;
    const int lrow = lane & 15, quad = lane >> 4;

    __shared__ bf16 skh[64 * 128];
    __shared__ bf16 skl[64 * 128];
    __shared__ bf16 svt[128 * 64];
    __shared__ bf16 sp[4][16 * SPLD];
    __shared__ float samadd[S_];

    const size_t kbase = (size_t)bh * S_ * HD_;
    const size_t vbase = (size_t)bh * HD_ * S_;

    {
        int j = t * 8;
        float4 a0 = *(const float4*)(am + b * S_ + j);
        float4 a1 = *(const float4*)(am + b * S_ + j + 4);
        float4 r0 = {(1.0f - a0.x) * -10000.0f, (1.0f - a0.y) * -10000.0f,
                     (1.0f - a0.z) * -10000.0f, (1.0f - a0.w) * -10000.0f};
        float4 r1 = {(1.0f - a1.x) * -10000.0f, (1.0f - a1.y) * -10000.0f,
                     (1.0f - a1.z) * -10000.0f, (1.0f - a1.w) * -10000.0f};
        *(float4*)&samadd[j] = r0;
        *(float4*)&samadd[j + 4] = r1;
    }

    const int qrow = i0 + wave * 16 + lrow;
    bf16x8 qhf[4], qlf[4];
#pragma unroll
    for (int c = 0; c < 4; c++) {
        qhf[c] = *(const bf16x8*)&qh_[kbase + (size_t)qrow * HD_ + c * 32 + quad * 8];
        qlf[c] = *(const bf16x8*)&ql_[kbase + (size_t)qrow * HD_ + c * 32 + quad * 8];
    }

    u32x4 kpre[8], vpre[4];
    auto issueKV = [&](int j0) {
#pragma unroll
        for (int p = 0; p < 4; p++) {
            int rb = wave * 16 + p * 4;
            int r = rb + (lane >> 4);
            int gl = ((lane & 15) ^ (r & 7)) * 8;
            kpre[p]     = *(const u32x4*)(kh_ + kbase + (size_t)(j0 + r) * HD_ + gl);
            kpre[4 + p] = *(const u32x4*)(kl_ + kbase + (size_t)(j0 + r) * HD_ + gl);
        }
#pragma unroll
        for (int p = 0; p < 4; p++) {
            int db = wave * 32 + p * 8;
            int d = db + (lane >> 3);
            int gl = ((lane & 7) ^ (d & 7)) * 8;
            vpre[p] = *(const u32x4*)(vt_ + vbase + (size_t)d * S_ + j0 + gl);
        }
    };
    auto writeKV = [&]() {
#pragma unroll
        for (int p = 0; p < 4; p++) {
            int rb = wave * 16 + p * 4;
            *(u32x4*)&skh[rb * 128 + lane * 8] = kpre[p];
            *(u32x4*)&skl[rb * 128 + lane * 8] = kpre[4 + p];
        }
#pragma unroll
        for (int p = 0; p < 4; p++) {
            int db = wave * 32 + p * 8;
            *(u32x4*)&svt[db * 64 + lane * 8] = vpre[p];
        }
    };

    float m_i[4], l_i[4];
    f32x4 O[8];
#pragma unroll
    for (int r = 0; r < 4; r++) { m_i[r] = -INFINITY; l_i[r] = 0.f; }
#pragma unroll
    for (int n2 = 0; n2 < 8; n2++) O[n2] = (f32x4){0.f, 0.f, 0.f, 0.f};

    const float scale = 0.08838834764831845f;

    issueKV(0);
    __syncthreads();

    for (int j0 = 0; j0 <= i0; j0 += 64) {
        BAR();
        writeKV();
        if (j0 + 64 <= i0) issueKV(j0 + 64);
        asm volatile("s_waitcnt lgkmcnt(0)" ::: "memory");
        BAR();

        float amadd[4];
#pragma unroll
        for (int nt = 0; nt < 4; nt++)
            amadd[nt] = samadd[j0 + nt * 16 + lrow];

        f32x4 s4[4];
#pragma unroll
        for (int nt = 0; nt < 4; nt++) s4[nt] = (f32x4){0.f, 0.f, 0.f, 0.f};
        __builtin_amdgcn_s_setprio(1);
#pragma unroll
        for (int c = 0; c < 4; c++) {
#pragma unroll
            for (int nt = 0; nt < 4; nt++) {
                int ka = (nt * 16 + lrow) * 128 + (((c * 4 + quad) ^ (lrow & 7)) * 8);
                bf16x8 kb8 = *(const bf16x8*)&skh[ka];
                bf16x8 lb8 = *(const bf16x8*)&skl[ka];
                s4[nt] = mfma16(qhf[c], kb8, s4[nt]);
                s4[nt] = mfma16(qhf[c], lb8, s4[nt]);
                s4[nt] = mfma16(qlf[c], kb8, s4[nt]);
            }
        }
        __builtin_amdgcn_s_setprio(0);

        const bool diag = (j0 == i0);
#pragma unroll
        for (int r = 0; r < 4; r++) {
            const int rrow = wave * 16 + quad * 4 + r;
            float sv[4], pw[4];
            float mx = -INFINITY;
#pragma unroll
            for (int nt = 0; nt < 4; nt++) {
                float xv = s4[nt][r] * scale + amadd[nt];
                if (diag && (nt * 16 + lrow) > rrow) xv = -INFINITY;
                sv[nt] = xv;
                mx = fmaxf(mx, xv);
            }
#pragma unroll
            for (int off = 1; off < 16; off <<= 1) mx = fmaxf(mx, __shfl_xor(mx, off));
            float mnew = fmaxf(m_i[r], mx);
            float alpha = __expf(m_i[r] - mnew);
            float ps = 0.f;
#pragma unroll
            for (int nt = 0; nt < 4; nt++) { pw[nt] = __expf(sv[nt] - mnew); ps += pw[nt]; }
#pragma unroll
            for (int off = 1; off < 16; off <<= 1) ps += __shfl_xor(ps, off);
            l_i[r] = l_i[r] * alpha + ps;
            m_i[r] = mnew;
#pragma unroll
            for (int n2 = 0; n2 < 8; n2++) O[n2][r] *= alpha;
#pragma unroll
            for (int nt = 0; nt < 4; nt++)
                sp[wave][(quad * 4 + r) * SPLD + nt * 16 + lrow] = (bf16)pw[nt];
        }
        asm volatile("s_waitcnt lgkmcnt(0)" ::: "memory");

        __builtin_amdgcn_s_setprio(1);
#pragma unroll
        for (int k2 = 0; k2 < 2; k2++) {
            bf16x8 pf = *(const bf16x8*)&sp[wave][lrow * SPLD + k2 * 32 + quad * 8];
            const int gp = ((quad + k2 * 4) ^ (lrow & 7)) * 8;
#pragma unroll
            for (int n2 = 0; n2 < 8; n2++) {
                bf16x8 vf8 = *(const bf16x8*)&svt[(n2 * 16 + lrow) * 64 + gp];
                O[n2] = mfma16(pf, vf8, O[n2]);
            }
        }
        __builtin_amdgcn_s_setprio(0);
    }

    float inv[4];
#pragma unroll
    for (int r = 0; r < 4; r++) inv[r] = 1.0f / l_i[r];
#pragma unroll
    for (int n2 = 0; n2 < 8; n2++)
#pragma unroll
        for (int r = 0; r < 4; r++) {
            int srow = i0 + wave * 16 + quad * 4 + r;
            outp[((size_t)(b * S_ + srow)) * D_ + h * HD_ + n2 * 16 + lrow] =
                (bf16)(O[n2][r] * inv[r]);
        }
}

// =================== launch ===================
extern "C" void kernel_launch(void* const* d_in, const int* in_sizes, int n_in,
                              void* d_out, int out_size, void* d_ws, size_t ws_size,
                              hipStream_t stream) {
    const float* x  = (const float*)d_in[0];
    const float* qm = (const float*)d_in[1];
    const float* km = (const float*)d_in[2];
    const float* vm = (const float*)d_in[3];
    const float* om = (const float*)d_in[4];
    const float* hm = (const float*)d_in[5];
    const float* am = (const float*)d_in[6];
    const float* sw = (const float*)d_in[7];
    float* out = (float*)d_out;

    const size_t P = (size_t)B_ * H_ * S_ * HD_ * sizeof(bf16);   // 16 MiB
    char* ws = (char*)d_ws;
    bf16* xh = (bf16*)(ws + 0 * P);
    bf16* xl = (bf16*)(ws + 1 * P);
    bf16* qh = (bf16*)(ws + 2 * P);
    bf16* ql = (bf16*)(ws + 3 * P);
    bf16* kh = (bf16*)(ws + 4 * P);
    bf16* kl = (bf16*)(ws + 5 * P);
    bf16* attn_out = xh;
    bf16* vmb = xl;
    bf16* omb = qh;
    bf16* vt  = (bf16*)d_out;
    bf16* qmb = (bf16*)((char*)d_out + 16u * 1024 * 1024);
    bf16* kmb = (bf16*)((char*)d_out + 24u * 1024 * 1024);

    precast_all<<<8192, 256, 0, stream>>>(x, xh, xl, qm, qmb, km, kmb, sw);

    // q/k projection: 256x256 8-phase template, virtual K=4096, 256 blocks = 1/CU
    gemm8x<<<dim3(16, 16), 512, 0, stream>>>(
        xh, xl, qmb, kmb, hm, qh, ql, kh, kl, 64);

    // v projection (hi only): 128x128 tiles, 512 blocks; writes V^T directly
    precast_mask<<<2048, 256, 0, stream>>>(vm, vmb, sw);
    gemm2p<128, 128, 1><<<dim3(16, 32), 256, 0, stream>>>(
        xh, nullptr, vmb, nullptr, hm,
        nullptr, nullptr, nullptr, nullptr, vt, nullptr, 64);

    // attention: 1024 blocks, XCD-locality mapping
    attn_kernel<<<1024, 256, 0, stream>>>(qh, ql, kh, kl, vt, am, attn_out);

    // output projection: 128x128 tiles, 512 blocks, f32 out
    precast_mask<<<2048, 256, 0, stream>>>(om, omb, sw);
    gemm2p<128, 128, 2><<<dim3(16, 32), 256, 0, stream>>>(
        attn_out, nullptr, omb, nullptr, hm,
        nullptr, nullptr, nullptr, nullptr, nullptr, out, 64);
}

// Round 7
// 492.095 us; speedup vs baseline: 1.0062x; 1.0062x over previous
//
#include <hip/hip_runtime.h>

#define B_  2
#define S_  2048
#define D_  2048
#define H_  16
#define HD_ 128

typedef __bf16 bf16;
typedef __bf16 bf16x4 __attribute__((ext_vector_type(4)));
typedef __bf16 bf16x8 __attribute__((ext_vector_type(8)));
typedef float  f32x4  __attribute__((ext_vector_type(4)));
typedef unsigned int u32x4 __attribute__((ext_vector_type(4)));

// async global->LDS 16B copy: lds dst = wave-uniform base + lane*16
__device__ __forceinline__ void gld_lds16(const void* g, void* l) {
    __builtin_amdgcn_global_load_lds(
        (const __attribute__((address_space(1))) unsigned int*)g,
        (__attribute__((address_space(3))) unsigned int*)l, 16, 0, 0);
}

__device__ __forceinline__ f32x4 mfma16(bf16x8 a, bf16x8 b, f32x4 c) {
    return __builtin_amdgcn_mfma_f32_16x16x32_bf16(a, b, c, 0, 0, 0);
}

// raw barrier with compiler memory fence (does NOT drain vmcnt - that's the point)
#define BAR()  asm volatile("s_barrier" ::: "memory")

// ---------------- fused precast: x -> hi/lo planes, qm/km -> bf16 ----------------
__global__ __launch_bounds__(256)
void precast_all(const float* __restrict__ x, bf16* __restrict__ xh,
                 bf16* __restrict__ xl,
                 const float* __restrict__ qm, bf16* __restrict__ qmb,
                 const float* __restrict__ km, bf16* __restrict__ kmb,
                 const float* __restrict__ swp) {
    int bid = blockIdx.x;
    if (bid < 4096) {
        int i = (bid * 256 + threadIdx.x) * 8;
        float4 a = *(const float4*)(x + i);
        float4 b = *(const float4*)(x + i + 4);
        float av[8] = {a.x, a.y, a.z, a.w, b.x, b.y, b.z, b.w};
        bf16x8 h8, l8;
#pragma unroll
        for (int e = 0; e < 8; e++) {
            bf16 hv = (bf16)av[e];
            h8[e] = hv;
            l8[e] = (bf16)(av[e] - (float)hv);
        }
        *(bf16x8*)(xh + i) = h8;
        *(bf16x8*)(xl + i) = l8;
        return;
    }
    const float sw = swp[0];
    bid -= 4096;
    const float* src = qm; bf16* dst = qmb;
    if (bid >= 2048) { src = km; dst = kmb; bid -= 2048; }
    int i = (bid * 256 + threadIdx.x) * 8;
    float4 a = *(const float4*)(src + i);
    float4 b = *(const float4*)(src + i + 4);
    bf16x8 o;
    o[0] = (bf16)(a.x * sw); o[1] = (bf16)(a.y * sw);
    o[2] = (bf16)(a.z * sw); o[3] = (bf16)(a.w * sw);
    o[4] = (bf16)(b.x * sw); o[5] = (bf16)(b.y * sw);
    o[6] = (bf16)(b.z * sw); o[7] = (bf16)(b.w * sw);
    *(bf16x8*)(dst + i) = o;
}

// ---------------- precast masks: f32 * sw -> bf16 (single mask) ----------------
__global__ __launch_bounds__(256)
void precast_mask(const float* __restrict__ s0, bf16* __restrict__ d0,
                  const float* __restrict__ swp) {
    const float sw = swp[0];
    int i = (blockIdx.x * 256 + threadIdx.x) * 8;
    float4 a = *(const float4*)(s0 + i);
    float4 b = *(const float4*)(s0 + i + 4);
    bf16x8 o;
    o[0] = (bf16)(a.x * sw); o[1] = (bf16)(a.y * sw);
    o[2] = (bf16)(a.z * sw); o[3] = (bf16)(a.w * sw);
    o[4] = (bf16)(b.x * sw); o[5] = (bf16)(b.y * sw);
    o[6] = (bf16)(b.z * sw); o[7] = (bf16)(b.w * sw);
    *(bf16x8*)(d0 + i) = o;
}

// ========= 256x256 2-phase GEMM, 8 waves, 1 block/CU (q/k projection) =========
// Round-5 relaxed schedule, re-parameterized for arithmetic intensity: staged
// bytes per FLOP drop 1.5x vs 256x128 (staging-BW is the measured bottleneck:
// matrix pipe only ~11% busy; LDS-fill rate ~10.5 TB/s is the wall).
// 8 waves in 2M x 4N grid; per wave 128x64 out (IM=8, JN=4); BK=32; LDS 64 KiB
// (2 buffers). Same swizzle, same vmcnt(2) FIFO numerology (2-issue stages),
// same 2 barriers/kt. Virtual K=4096: kt 0..63 = xh plane, 64..127 = xl.
__global__ __launch_bounds__(512, 1)
void gemm2p8(const bf16* __restrict__ Ah_g, const bf16* __restrict__ Al_g,
             const bf16* __restrict__ Bq, const bf16* __restrict__ Bk,
             const float* __restrict__ hm,
             bf16* __restrict__ o_qh, bf16* __restrict__ o_ql,
             bf16* __restrict__ o_kh, bf16* __restrict__ o_kl,
             int nt) {
    constexpr int BM = 256, BN = 256;
    constexpr int IM = 8, JN = 4, IH = 4;
    constexpr int BUFE = (BM + BN) * 32;       // 16384 bf16 = 32 KiB per buffer
    __shared__ bf16 sm[2 * BUFE];              // 64 KiB

    const int t = threadIdx.x;
    const int wave = t >> 6, lane = t & 63;
    const int lrow = lane & 15, quad = lane >> 4;
    const int wr = wave >> 2, wc = wave & 3;   // 2M x 4N

    // XCD-aware bijective swizzle (256 blocks = 8*32)
    const int gx = gridDim.x;                  // 16
    const int id0 = blockIdx.y * gx + blockIdx.x;
    const int id = (id0 & 7) * 32 + (id0 >> 3);
    const int m0 = (id / gx) * BM, n0 = (id % gx) * BN;

    const int nsec = n0 & (D_ - 1);
    const bf16* Bg = (n0 >= D_) ? Bk : Bq;

    const int arow = wr * 128 + lrow;
    const int brow = wc * 64 + lrow;
    const int gsw = (quad ^ ((lrow >> 1) & 3)) * 8;     // swizzled read group

    // staging lane constants: 16 rows x 4 groups per 1KB issue
    const int srr = lane >> 2, spg = lane & 3;
    const int ssw = (spg ^ ((srr >> 1) & 3)) * 8;       // swizzled source col

    auto stage_A = [&](int kt, int pbuf) {
        const bf16* As = (kt >= 64) ? Al_g : Ah_g;
        const int kc = (kt & 63) * 32;
        bf16* buf = sm + pbuf * BUFE;
#pragma unroll
        for (int pp = 0; pp < 2; pp++) {       // 8 waves x 2 x 16 rows = 256
            int r0 = wave * 32 + pp * 16;
            gld_lds16(As + (size_t)(m0 + r0 + srr) * D_ + kc + ssw,
                      buf + r0 * 32);
        }
    };
    auto stage_B = [&](int kt, int pbuf) {
        const int kc = (kt & 63) * 32;
        bf16* buf = sm + pbuf * BUFE + BM * 32;
#pragma unroll
        for (int pp = 0; pp < 2; pp++) {
            int r0 = wave * 32 + pp * 16;
            gld_lds16(Bg + (size_t)(nsec + r0 + srr) * D_ + kc + ssw,
                      buf + r0 * 32);
        }
    };

    f32x4 acc[IM][JN];
#pragma unroll
    for (int i = 0; i < IM; i++)
#pragma unroll
        for (int j = 0; j < JN; j++) acc[i][j] = (f32x4){0.f, 0.f, 0.f, 0.f};

    // prologue: buf0 full, buf1 B (buf1 A issued at top of kt=0)
    stage_A(0, 0); stage_B(0, 0); stage_B(1, 1);

    int p = 0;
    for (int kt = 0; kt < nt; ++kt) {
        // FIFO/wave: [A(kt) x2, B(kt+1) x2] after prologue pattern ->
        // vmcnt(2) completes A(kt) and B(kt); keeps B(kt+1) flying.
        if (kt < nt - 1) asm volatile("s_waitcnt vmcnt(2)" ::: "memory");
        else             asm volatile("s_waitcnt vmcnt(0)" ::: "memory");
        BAR();                                  // buf[p] globally ready
        if (kt + 1 < nt) stage_A(kt + 1, p ^ 1);

        const bf16* Ab = sm + p * BUFE;
        const bf16* Bb = Ab + BM * 32;
        bf16x8 a[IH], b[JN];

        // ---- phase A: read B (all) + A rows [0,IH); MFMA upper half
#pragma unroll
        for (int j = 0; j < JN; j++)
            b[j] = *(const bf16x8*)&Bb[(brow + j * 16) * 32 + gsw];
#pragma unroll
        for (int i = 0; i < IH; i++)
            a[i] = *(const bf16x8*)&Ab[(arow + i * 16) * 32 + gsw];
        __builtin_amdgcn_s_setprio(1);
#pragma unroll
        for (int i = 0; i < IH; i++)
#pragma unroll
            for (int j = 0; j < JN; j++)
                acc[i][j] = mfma16(a[i], b[j], acc[i][j]);
        __builtin_amdgcn_s_setprio(0);
        BAR();          // all waves' B reads retired (consumed by MFMAs above)

        if (kt + 2 < nt) stage_B(kt + 2, p);

        // ---- phase B: read A rows [IH,IM); MFMA lower half
#pragma unroll
        for (int i = 0; i < IH; i++)
            a[i] = *(const bf16x8*)&Ab[(arow + (IH + i) * 16) * 32 + gsw];
        __builtin_amdgcn_s_setprio(1);
#pragma unroll
        for (int i = 0; i < IH; i++)
#pragma unroll
            for (int j = 0; j < JN; j++)
                acc[IH + i][j] = mfma16(a[i], b[j], acc[IH + i][j]);
        __builtin_amdgcn_s_setprio(0);
        p ^= 1;
    }

    // epilogue: *hm, hi/lo split scatter (q or k section)
    const bool isq = (n0 < D_);
    bf16* oh = isq ? o_qh : o_kh;
    bf16* ol = isq ? o_ql : o_kl;
#pragma unroll
    for (int j = 0; j < JN; j++) {
        int nb = nsec + wc * 64 + j * 16;
        int h = nb >> 7;
        float hv = hm[h];
#pragma unroll
        for (int i = 0; i < IM; i++) {
            int mB = m0 + wr * 128 + i * 16 + quad * 4;
            int bb = mB >> 11, s = mB & (S_ - 1);
            size_t idx0 = (((size_t)bb * H_ + h) * S_ + s) * HD_ + (nb & 127) + lrow;
#pragma unroll
            for (int r = 0; r < 4; r++) {
                float v = acc[i][j][r] * hv;
                bf16 hvv = (bf16)v;
                bf16 lvv = (bf16)(v - (float)hvv);
                oh[idx0 + (size_t)r * HD_] = hvv;
                ol[idx0 + (size_t)r * HD_] = lvv;
            }
        }
    }
}

// =================== 2-phase double-buffered GEMM (v / out proj) =======
// round-5 relaxed structure (passing). MODE 1: v proj + V^T epilogue.
// MODE 2: out proj, f32 epilogue.
template<int BM, int BN, int MODE>
__global__ __launch_bounds__(256, 2)
void gemm2p(const bf16* __restrict__ Ah_g, const bf16* __restrict__ Al_g,
            const bf16* __restrict__ Bq, const bf16* __restrict__ Bk,
            const float* __restrict__ hm,
            bf16* __restrict__ o_qh, bf16* __restrict__ o_ql,
            bf16* __restrict__ o_kh, bf16* __restrict__ o_kl,
            bf16* __restrict__ o_vt, float* __restrict__ o_f32,
            int nt) {
    constexpr int IM = BM / 2 / 16;
    constexpr int JN = BN / 2 / 16;
    constexpr int IH = IM / 2;
    constexpr int ISSA = BM / 64;
    constexpr int ISSB = BN / 64;
    constexpr int BUFE = (BM + BN) * 32;
    constexpr int SMELEMS = (MODE == 1 && BN * (BM + 8) > 2 * BUFE)
                                ? BN * (BM + 8) : 2 * BUFE;
    __shared__ bf16 sm[SMELEMS];

    const int t = threadIdx.x;
    const int wave = t >> 6, lane = t & 63;
    const int lrow = lane & 15, quad = lane >> 4;
    const int wr = wave >> 1, wc = wave & 1;

    const int gx = gridDim.x;
    const int id0 = blockIdx.y * gx + blockIdx.x;
    const int nwg = gx * gridDim.y;
    const int id = (id0 & 7) * (nwg >> 3) + (id0 >> 3);
    const int m0 = (id / gx) * BM, n0 = (id % gx) * BN;

    const int nsec = (MODE == 0) ? (n0 & (D_ - 1)) : n0;
    const bf16* Bg = (MODE == 0 && n0 >= D_) ? Bk : Bq;

    const int arow = wr * (BM / 2) + lrow;
    const int brow = wc * (BN / 2) + lrow;
    const int gsw = (quad ^ ((lrow >> 1) & 3)) * 8;

    const int srr = lane >> 2, spg = lane & 3;
    const int ssw = (spg ^ ((srr >> 1) & 3)) * 8;

    auto stage_A = [&](int kt, int pbuf) {
        const bf16* As = (MODE == 0 && kt >= 64) ? Al_g : Ah_g;
        const int kc = ((MODE == 0) ? (kt & 63) : kt) * 32;
        bf16* buf = sm + pbuf * BUFE;
#pragma unroll
        for (int pp = 0; pp < ISSA; pp++) {
            int r0 = wave * (BM / 4) + pp * 16;
            gld_lds16(As + (size_t)(m0 + r0 + srr) * D_ + kc + ssw,
                      buf + r0 * 32);
        }
    };
    auto stage_B = [&](int kt, int pbuf) {
        const int kc = ((MODE == 0) ? (kt & 63) : kt) * 32;
        bf16* buf = sm + pbuf * BUFE + BM * 32;
#pragma unroll
        for (int pp = 0; pp < ISSB; pp++) {
            int r0 = wave * (BN / 4) + pp * 16;
            gld_lds16(Bg + (size_t)(nsec + r0 + srr) * D_ + kc + ssw,
                      buf + r0 * 32);
        }
    };

    f32x4 acc[IM][JN];
#pragma unroll
    for (int i = 0; i < IM; i++)
#pragma unroll
        for (int j = 0; j < JN; j++) acc[i][j] = (f32x4){0.f, 0.f, 0.f, 0.f};

    stage_A(0, 0); stage_B(0, 0); stage_B(1, 1);

    int p = 0;
    for (int kt = 0; kt < nt; ++kt) {
        if (kt < nt - 1) asm volatile("s_waitcnt vmcnt(2)" ::: "memory");
        else             asm volatile("s_waitcnt vmcnt(0)" ::: "memory");
        BAR();
        if (kt + 1 < nt) stage_A(kt + 1, p ^ 1);

        const bf16* Ab = sm + p * BUFE;
        const bf16* Bb = Ab + BM * 32;
        bf16x8 a[IH], b[JN];

#pragma unroll
        for (int j = 0; j < JN; j++)
            b[j] = *(const bf16x8*)&Bb[(brow + j * 16) * 32 + gsw];
#pragma unroll
        for (int i = 0; i < IH; i++)
            a[i] = *(const bf16x8*)&Ab[(arow + i * 16) * 32 + gsw];
        __builtin_amdgcn_s_setprio(1);
#pragma unroll
        for (int i = 0; i < IH; i++)
#pragma unroll
            for (int j = 0; j < JN; j++)
                acc[i][j] = mfma16(a[i], b[j], acc[i][j]);
        __builtin_amdgcn_s_setprio(0);
        BAR();

        if (kt + 2 < nt) stage_B(kt + 2, p);

#pragma unroll
        for (int i = 0; i < IH; i++)
            a[i] = *(const bf16x8*)&Ab[(arow + (IH + i) * 16) * 32 + gsw];
        __builtin_amdgcn_s_setprio(1);
#pragma unroll
        for (int i = 0; i < IH; i++)
#pragma unroll
            for (int j = 0; j < JN; j++)
                acc[IH + i][j] = mfma16(a[i], b[j], acc[IH + i][j]);
        __builtin_amdgcn_s_setprio(0);
        p ^= 1;
    }

    if constexpr (MODE == 0) {
        const bool isq = (n0 < D_);
        bf16* oh = isq ? o_qh : o_kh;
        bf16* ol = isq ? o_ql : o_kl;
#pragma unroll
        for (int j = 0; j < JN; j++) {
            int nb = nsec + wc * (BN / 2) + j * 16;
            int h = nb >> 7;
            float hv = hm[h];
#pragma unroll
            for (int i = 0; i < IM; i++) {
                int mB = m0 + wr * (BM / 2) + i * 16 + quad * 4;
                int bb = mB >> 11, s = mB & (S_ - 1);
                size_t idx0 = (((size_t)bb * H_ + h) * S_ + s) * HD_ + (nb & 127) + lrow;
#pragma unroll
                for (int r = 0; r < 4; r++) {
                    float v = acc[i][j][r] * hv;
                    bf16 hvv = (bf16)v;
                    bf16 lvv = (bf16)(v - (float)hvv);
                    oh[idx0 + (size_t)r * HD_] = hvv;
                    ol[idx0 + (size_t)r * HD_] = lvv;
                }
            }
        }
    }
    if constexpr (MODE == 1) {
        __syncthreads();
        bf16* tr = sm;
#pragma unroll
        for (int j = 0; j < JN; j++) {
            int nl = wc * (BN / 2) + j * 16 + lrow;
            float hv = hm[(n0 + nl) >> 7];
#pragma unroll
            for (int i = 0; i < IM; i++) {
                int ml = wr * (BM / 2) + i * 16 + quad * 4;
                bf16x4 pk;
#pragma unroll
                for (int r = 0; r < 4; r++) pk[r] = (bf16)(acc[i][j][r] * hv);
                *(bf16x4*)&tr[nl * 136 + ml] = pk;
            }
        }
        __syncthreads();
        const int bI = m0 >> 11;
        const int s0 = m0 & (S_ - 1);
#pragma unroll
        for (int w = 0; w < 8; w++) {
            int nrow = w * 16 + (t >> 4);
            int c = t & 15;
            bf16x8 vv = *(const bf16x8*)&tr[nrow * 136 + c * 8];
            int ng = n0 + nrow;
            int h = ng >> 7, hd = ng & 127;
            *(bf16x8*)&o_vt[((size_t)(bI * H_ + h) * HD_ + hd) * S_ + s0 + c * 8] = vv;
        }
    }
    if constexpr (MODE == 2) {
#pragma unroll
        for (int j = 0; j < JN; j++) {
            int n = n0 + wc * (BN / 2) + j * 16 + lrow;
#pragma unroll
            for (int i = 0; i < IM; i++) {
                int mB = m0 + wr * (BM / 2) + i * 16 + quad * 4;
#pragma unroll
                for (int r = 0; r < 4; r++)
                    o_f32[(size_t)(mB + r) * D_ + n] = acc[i][j][r];
            }
        }
    }
}

// =================== causal flash attention (unchanged, round-5 passing) =======
#define SPLD 72

__global__ __launch_bounds__(256, 2)
void attn_kernel(const bf16* __restrict__ qh_, const bf16* __restrict__ ql_,
                 const bf16* __restrict__ kh_, const bf16* __restrict__ kl_,
                 const bf16* __restrict__ vt_, const float* __restrict__ am,
                 bf16* __restrict__ outp) {
    const int id = blockIdx.x;
    const int xcd = id & 7, slot = id >> 3;
    const int bh = xcd * 4 + (slot & 3);
    const int qblk = 31 - (slot >> 2);
    const int b = bh >> 4, h = bh & 15;
    const int i0 = qblk * 64;
    const int t = threadIdx.x, wave = t >> 6, lane = t & 63;
    const int lrow = lane & 15, quad = lane >> 4;

    __shared__ bf16 skh[64 * 128];
    __shared__ bf16 skl[64 * 128];
    __shared__ bf16 svt[128 * 64];
    __shared__ bf16 sp[4][16 * SPLD];
    __shared__ float samadd[S_];

    const size_t kbase = (size_t)bh * S_ * HD_;
    const size_t vbase = (size_t)bh * HD_ * S_;

    {
        int j = t * 8;
        float4 a0 = *(const float4*)(am + b * S_ + j);
        float4 a1 = *(const float4*)(am + b * S_ + j + 4);
        float4 r0 = {(1.0f - a0.x) * -10000.0f, (1.0f - a0.y) * -10000.0f,
                     (1.0f - a0.z) * -10000.0f, (1.0f - a0.w) * -10000.0f};
        float4 r1 = {(1.0f - a1.x) * -10000.0f, (1.0f - a1.y) * -10000.0f,
                     (1.0f - a1.z) * -10000.0f, (1.0f - a1.w) * -10000.0f};
        *(float4*)&samadd[j] = r0;
        *(float4*)&samadd[j + 4] = r1;
    }

    const int qrow = i0 + wave * 16 + lrow;
    bf16x8 qhf[4], qlf[4];
#pragma unroll
    for (int c = 0; c < 4; c++) {
        qhf[c] = *(const bf16x8*)&qh_[kbase + (size_t)qrow * HD_ + c * 32 + quad * 8];
        qlf[c] = *(const bf16x8*)&ql_[kbase + (size_t)qrow * HD_ + c * 32 + quad * 8];
    }

    u32x4 kpre[8], vpre[4];
    auto issueKV = [&](int j0) {
#pragma unroll
        for (int p = 0; p < 4; p++) {
            int rb = wave * 16 + p * 4;
            int r = rb + (lane >> 4);
            int gl = ((lane & 15) ^ (r & 7)) * 8;
            kpre[p]     = *(const u32x4*)(kh_ + kbase + (size_t)(j0 + r) * HD_ + gl);
            kpre[4 + p] = *(const u32x4*)(kl_ + kbase + (size_t)(j0 + r) * HD_ + gl);
        }
#pragma unroll
        for (int p = 0; p < 4; p++) {
            int db = wave * 32 + p * 8;
            int d = db + (lane >> 3);
            int gl = ((lane & 7) ^ (d & 7)) * 8;
            vpre[p] = *(const u32x4*)(vt_ + vbase + (size_t)d * S_ + j0 + gl);
        }
    };
    auto writeKV = [&]() {
#pragma unroll
        for (int p = 0; p < 4; p++) {
            int rb = wave * 16 + p * 4;
            *(u32x4*)&skh[rb * 128 + lane * 8] = kpre[p];
            *(u32x4*)&skl[rb * 128 + lane * 8] = kpre[4 + p];
        }
#pragma unroll
        for (int p = 0; p < 4; p++) {
            int db = wave * 32 + p * 8;
            *(u32x4*)&svt[db * 64 + lane * 8] = vpre[p];
        }
    };

    float m_i[4], l_i[4];
    f32x4 O[8];
#pragma unroll
    for (int r = 0; r < 4; r++) { m_i[r] = -INFINITY; l_i[r] = 0.f; }
#pragma unroll
    for (int n2 = 0; n2 < 8; n2++) O[n2] = (f32x4){0.f, 0.f, 0.f, 0.f};

    const float scale = 0.08838834764831845f;

    issueKV(0);
    __syncthreads();

    for (int j0 = 0; j0 <= i0; j0 += 64) {
        BAR();
        writeKV();
        if (j0 + 64 <= i0) issueKV(j0 + 64);
        asm volatile("s_waitcnt lgkmcnt(0)" ::: "memory");
        BAR();

        float amadd[4];
#pragma unroll
        for (int nt = 0; nt < 4; nt++)
            amadd[nt] = samadd[j0 + nt * 16 + lrow];

        f32x4 s4[4];
#pragma unroll
        for (int nt = 0; nt < 4; nt++) s4[nt] = (f32x4){0.f, 0.f, 0.f, 0.f};
        __builtin_amdgcn_s_setprio(1);
#pragma unroll
        for (int c = 0; c < 4; c++) {
#pragma unroll
            for (int nt = 0; nt < 4; nt++) {
                int ka = (nt * 16 + lrow) * 128 + (((c * 4 + quad) ^ (lrow & 7)) * 8);
                bf16x8 kb8 = *(const bf16x8*)&skh[ka];
                bf16x8 lb8 = *(const bf16x8*)&skl[ka];
                s4[nt] = mfma16(qhf[c], kb8, s4[nt]);
                s4[nt] = mfma16(qhf[c], lb8, s4[nt]);
                s4[nt] = mfma16(qlf[c], kb8, s4[nt]);
            }
        }
        __builtin_amdgcn_s_setprio(0);

        const bool diag = (j0 == i0);
#pragma unroll
        for (int r = 0; r < 4; r++) {
            const int rrow = wave * 16 + quad * 4 + r;
            float sv[4], pw[4];
            float mx = -INFINITY;
#pragma unroll
            for (int nt = 0; nt < 4; nt++) {
                float xv = s4[nt][r] * scale + amadd[nt];
                if (diag && (nt * 16 + lrow) > rrow) xv = -INFINITY;
                sv[nt] = xv;
                mx = fmaxf(mx, xv);
            }
#pragma unroll
            for (int off = 1; off < 16; off <<= 1) mx = fmaxf(mx, __shfl_xor(mx, off));
            float mnew = fmaxf(m_i[r], mx);
            float alpha = __expf(m_i[r] - mnew);
            float ps = 0.f;
#pragma unroll
            for (int nt = 0; nt < 4; nt++) { pw[nt] = __expf(sv[nt] - mnew); ps += pw[nt]; }
#pragma unroll
            for (int off = 1; off < 16; off <<= 1) ps += __shfl_xor(ps, off);
            l_i[r] = l_i[r] * alpha + ps;
            m_i[r] = mnew;
#pragma unroll
            for (int n2 = 0; n2 < 8; n2++) O[n2][r] *= alpha;
#pragma unroll
            for (int nt = 0; nt < 4; nt++)
                sp[wave][(quad * 4 + r) * SPLD + nt * 16 + lrow] = (bf16)pw[nt];
        }
        asm volatile("s_waitcnt lgkmcnt(0)" ::: "memory");

        __builtin_amdgcn_s_setprio(1);
#pragma unroll
        for (int k2 = 0; k2 < 2; k2++) {
            bf16x8 pf = *(const bf16x8*)&sp[wave][lrow * SPLD + k2 * 32 + quad * 8];
            const int gp = ((quad + k2 * 4) ^ (lrow & 7)) * 8;
#pragma unroll
            for (int n2 = 0; n2 < 8; n2++) {
                bf16x8 vf8 = *(const bf16x8*)&svt[(n2 * 16 + lrow) * 64 + gp];
                O[n2] = mfma16(pf, vf8, O[n2]);
            }
        }
        __builtin_amdgcn_s_setprio(0);
    }

    float inv[4];
#pragma unroll
    for (int r = 0; r < 4; r++) inv[r] = 1.0f / l_i[r];
#pragma unroll
    for (int n2 = 0; n2 < 8; n2++)
#pragma unroll
        for (int r = 0; r < 4; r++) {
            int srow = i0 + wave * 16 + quad * 4 + r;
            outp[((size_t)(b * S_ + srow)) * D_ + h * HD_ + n2 * 16 + lrow] =
                (bf16)(O[n2][r] * inv[r]);
        }
}

// =================== launch ===================
extern "C" void kernel_launch(void* const* d_in, const int* in_sizes, int n_in,
                              void* d_out, int out_size, void* d_ws, size_t ws_size,
                              hipStream_t stream) {
    const float* x  = (const float*)d_in[0];
    const float* qm = (const float*)d_in[1];
    const float* km = (const float*)d_in[2];
    const float* vm = (const float*)d_in[3];
    const float* om = (const float*)d_in[4];
    const float* hm = (const float*)d_in[5];
    const float* am = (const float*)d_in[6];
    const float* sw = (const float*)d_in[7];
    float* out = (float*)d_out;

    const size_t P = (size_t)B_ * H_ * S_ * HD_ * sizeof(bf16);   // 16 MiB
    char* ws = (char*)d_ws;
    bf16* xh = (bf16*)(ws + 0 * P);
    bf16* xl = (bf16*)(ws + 1 * P);
    bf16* qh = (bf16*)(ws + 2 * P);
    bf16* ql = (bf16*)(ws + 3 * P);
    bf16* kh = (bf16*)(ws + 4 * P);
    bf16* kl = (bf16*)(ws + 5 * P);
    bf16* attn_out = xh;
    bf16* vmb = xl;
    bf16* omb = qh;
    bf16* vt  = (bf16*)d_out;
    bf16* qmb = (bf16*)((char*)d_out + 16u * 1024 * 1024);
    bf16* kmb = (bf16*)((char*)d_out + 24u * 1024 * 1024);

    precast_all<<<8192, 256, 0, stream>>>(x, xh, xl, qm, qmb, km, kmb, sw);

    // q/k projection: 256x256 tiles, 8 waves, virtual K=4096, 256 blocks = 1/CU
    gemm2p8<<<dim3(16, 16), 512, 0, stream>>>(
        xh, xl, qmb, kmb, hm, qh, ql, kh, kl, 128);

    // v projection (hi only): 128x128 tiles, 512 blocks; writes V^T directly
    precast_mask<<<2048, 256, 0, stream>>>(vm, vmb, sw);
    gemm2p<128, 128, 1><<<dim3(16, 32), 256, 0, stream>>>(
        xh, nullptr, vmb, nullptr, hm,
        nullptr, nullptr, nullptr, nullptr, vt, nullptr, 64);

    // attention: 1024 blocks, XCD-locality mapping
    attn_kernel<<<1024, 256, 0, stream>>>(qh, ql, kh, kl, vt, am, attn_out);

    // output projection: 128x128 tiles, 512 blocks, f32 out
    precast_mask<<<2048, 256, 0, stream>>>(om, omb, sw);
    gemm2p<128, 128, 2><<<dim3(16, 32), 256, 0, stream>>>(
        attn_out, nullptr, omb, nullptr, hm,
        nullptr, nullptr, nullptr, nullptr, nullptr, out, 64);
}

// Round 8
// 474.704 us; speedup vs baseline: 1.0431x; 1.0366x over previous
//
#include <hip/hip_runtime.h>

#define B_  2
#define S_  2048
#define D_  2048
#define H_  16
#define HD_ 128

typedef __bf16 bf16;
typedef __bf16 bf16x4 __attribute__((ext_vector_type(4)));
typedef __bf16 bf16x8 __attribute__((ext_vector_type(8)));
typedef float  f32x4  __attribute__((ext_vector_type(4)));
typedef unsigned int u32x4 __attribute__((ext_vector_type(4)));

// async global->LDS 16B copy: lds dst = wave-uniform base + lane*16
__device__ __forceinline__ void gld_lds16(const void* g, void* l) {
    __builtin_amdgcn_global_load_lds(
        (const __attribute__((address_space(1))) unsigned int*)g,
        (__attribute__((address_space(3))) unsigned int*)l, 16, 0, 0);
}

__device__ __forceinline__ f32x4 mfma16(bf16x8 a, bf16x8 b, f32x4 c) {
    return __builtin_amdgcn_mfma_f32_16x16x32_bf16(a, b, c, 0, 0, 0);
}

// raw barrier with compiler memory fence (does NOT drain vmcnt - that's the point)
#define BAR()  asm volatile("s_barrier" ::: "memory")

// ---------------- fused precast: x -> hi/lo planes, qm/km -> bf16 ----------------
__global__ __launch_bounds__(256)
void precast_all(const float* __restrict__ x, bf16* __restrict__ xh,
                 bf16* __restrict__ xl,
                 const float* __restrict__ qm, bf16* __restrict__ qmb,
                 const float* __restrict__ km, bf16* __restrict__ kmb,
                 const float* __restrict__ swp) {
    int bid = blockIdx.x;
    if (bid < 4096) {
        int i = (bid * 256 + threadIdx.x) * 8;
        float4 a = *(const float4*)(x + i);
        float4 b = *(const float4*)(x + i + 4);
        float av[8] = {a.x, a.y, a.z, a.w, b.x, b.y, b.z, b.w};
        bf16x8 h8, l8;
#pragma unroll
        for (int e = 0; e < 8; e++) {
            bf16 hv = (bf16)av[e];
            h8[e] = hv;
            l8[e] = (bf16)(av[e] - (float)hv);
        }
        *(bf16x8*)(xh + i) = h8;
        *(bf16x8*)(xl + i) = l8;
        return;
    }
    const float sw = swp[0];
    bid -= 4096;
    const float* src = qm; bf16* dst = qmb;
    if (bid >= 2048) { src = km; dst = kmb; bid -= 2048; }
    int i = (bid * 256 + threadIdx.x) * 8;
    float4 a = *(const float4*)(src + i);
    float4 b = *(const float4*)(src + i + 4);
    bf16x8 o;
    o[0] = (bf16)(a.x * sw); o[1] = (bf16)(a.y * sw);
    o[2] = (bf16)(a.z * sw); o[3] = (bf16)(a.w * sw);
    o[4] = (bf16)(b.x * sw); o[5] = (bf16)(b.y * sw);
    o[6] = (bf16)(b.z * sw); o[7] = (bf16)(b.w * sw);
    *(bf16x8*)(dst + i) = o;
}

// ---------------- precast masks: f32 * sw -> bf16 (single mask) ----------------
__global__ __launch_bounds__(256)
void precast_mask(const float* __restrict__ s0, bf16* __restrict__ d0,
                  const float* __restrict__ swp) {
    const float sw = swp[0];
    int i = (blockIdx.x * 256 + threadIdx.x) * 8;
    float4 a = *(const float4*)(s0 + i);
    float4 b = *(const float4*)(s0 + i + 4);
    bf16x8 o;
    o[0] = (bf16)(a.x * sw); o[1] = (bf16)(a.y * sw);
    o[2] = (bf16)(a.z * sw); o[3] = (bf16)(a.w * sw);
    o[4] = (bf16)(b.x * sw); o[5] = (bf16)(b.y * sw);
    o[6] = (bf16)(b.z * sw); o[7] = (bf16)(b.w * sw);
    *(bf16x8*)(d0 + i) = o;
}

// =================== 2-phase double-buffered GEMM (round-5 best, 481.6) =======
// 4 waves, 2 blocks/CU, relaxed inner loop (compiler counted lgkm waits).
// MODE 0: q/k proj (virtual K=4096). MODE 1: v proj + V^T epilogue.
// MODE 2: out proj, f32 epilogue.
template<int BM, int BN, int MODE>
__global__ __launch_bounds__(256, 2)
void gemm2p(const bf16* __restrict__ Ah_g, const bf16* __restrict__ Al_g,
            const bf16* __restrict__ Bq, const bf16* __restrict__ Bk,
            const float* __restrict__ hm,
            bf16* __restrict__ o_qh, bf16* __restrict__ o_ql,
            bf16* __restrict__ o_kh, bf16* __restrict__ o_kl,
            bf16* __restrict__ o_vt, float* __restrict__ o_f32,
            int nt) {
    constexpr int IM = BM / 2 / 16;
    constexpr int JN = BN / 2 / 16;
    constexpr int IH = IM / 2;
    constexpr int ISSA = BM / 64;
    constexpr int ISSB = BN / 64;
    constexpr int BUFE = (BM + BN) * 32;
    constexpr int SMELEMS = (MODE == 1 && BN * (BM + 8) > 2 * BUFE)
                                ? BN * (BM + 8) : 2 * BUFE;
    __shared__ bf16 sm[SMELEMS];

    const int t = threadIdx.x;
    const int wave = t >> 6, lane = t & 63;
    const int lrow = lane & 15, quad = lane >> 4;
    const int wr = wave >> 1, wc = wave & 1;

    const int gx = gridDim.x;
    const int id0 = blockIdx.y * gx + blockIdx.x;
    const int nwg = gx * gridDim.y;
    const int id = (id0 & 7) * (nwg >> 3) + (id0 >> 3);
    const int m0 = (id / gx) * BM, n0 = (id % gx) * BN;

    const int nsec = (MODE == 0) ? (n0 & (D_ - 1)) : n0;
    const bf16* Bg = (MODE == 0 && n0 >= D_) ? Bk : Bq;

    const int arow = wr * (BM / 2) + lrow;
    const int brow = wc * (BN / 2) + lrow;
    const int gsw = (quad ^ ((lrow >> 1) & 3)) * 8;

    const int srr = lane >> 2, spg = lane & 3;
    const int ssw = (spg ^ ((srr >> 1) & 3)) * 8;

    auto stage_A = [&](int kt, int pbuf) {
        const bf16* As = (MODE == 0 && kt >= 64) ? Al_g : Ah_g;
        const int kc = ((MODE == 0) ? (kt & 63) : kt) * 32;
        bf16* buf = sm + pbuf * BUFE;
#pragma unroll
        for (int pp = 0; pp < ISSA; pp++) {
            int r0 = wave * (BM / 4) + pp * 16;
            gld_lds16(As + (size_t)(m0 + r0 + srr) * D_ + kc + ssw,
                      buf + r0 * 32);
        }
    };
    auto stage_B = [&](int kt, int pbuf) {
        const int kc = ((MODE == 0) ? (kt & 63) : kt) * 32;
        bf16* buf = sm + pbuf * BUFE + BM * 32;
#pragma unroll
        for (int pp = 0; pp < ISSB; pp++) {
            int r0 = wave * (BN / 4) + pp * 16;
            gld_lds16(Bg + (size_t)(nsec + r0 + srr) * D_ + kc + ssw,
                      buf + r0 * 32);
        }
    };

    f32x4 acc[IM][JN];
#pragma unroll
    for (int i = 0; i < IM; i++)
#pragma unroll
        for (int j = 0; j < JN; j++) acc[i][j] = (f32x4){0.f, 0.f, 0.f, 0.f};

    stage_A(0, 0); stage_B(0, 0); stage_B(1, 1);

    int p = 0;
    for (int kt = 0; kt < nt; ++kt) {
        if (kt < nt - 1) asm volatile("s_waitcnt vmcnt(2)" ::: "memory");
        else             asm volatile("s_waitcnt vmcnt(0)" ::: "memory");
        BAR();
        if (kt + 1 < nt) stage_A(kt + 1, p ^ 1);

        const bf16* Ab = sm + p * BUFE;
        const bf16* Bb = Ab + BM * 32;
        bf16x8 a[IH], b[JN];

#pragma unroll
        for (int j = 0; j < JN; j++)
            b[j] = *(const bf16x8*)&Bb[(brow + j * 16) * 32 + gsw];
#pragma unroll
        for (int i = 0; i < IH; i++)
            a[i] = *(const bf16x8*)&Ab[(arow + i * 16) * 32 + gsw];
        __builtin_amdgcn_s_setprio(1);
#pragma unroll
        for (int i = 0; i < IH; i++)
#pragma unroll
            for (int j = 0; j < JN; j++)
                acc[i][j] = mfma16(a[i], b[j], acc[i][j]);
        __builtin_amdgcn_s_setprio(0);
        BAR();

        if (kt + 2 < nt) stage_B(kt + 2, p);

#pragma unroll
        for (int i = 0; i < IH; i++)
            a[i] = *(const bf16x8*)&Ab[(arow + (IH + i) * 16) * 32 + gsw];
        __builtin_amdgcn_s_setprio(1);
#pragma unroll
        for (int i = 0; i < IH; i++)
#pragma unroll
            for (int j = 0; j < JN; j++)
                acc[IH + i][j] = mfma16(a[i], b[j], acc[IH + i][j]);
        __builtin_amdgcn_s_setprio(0);
        p ^= 1;
    }

    if constexpr (MODE == 0) {
        const bool isq = (n0 < D_);
        bf16* oh = isq ? o_qh : o_kh;
        bf16* ol = isq ? o_ql : o_kl;
#pragma unroll
        for (int j = 0; j < JN; j++) {
            int nb = nsec + wc * (BN / 2) + j * 16;
            int h = nb >> 7;
            float hv = hm[h];
#pragma unroll
            for (int i = 0; i < IM; i++) {
                int mB = m0 + wr * (BM / 2) + i * 16 + quad * 4;
                int bb = mB >> 11, s = mB & (S_ - 1);
                size_t idx0 = (((size_t)bb * H_ + h) * S_ + s) * HD_ + (nb & 127) + lrow;
#pragma unroll
                for (int r = 0; r < 4; r++) {
                    float v = acc[i][j][r] * hv;
                    bf16 hvv = (bf16)v;
                    bf16 lvv = (bf16)(v - (float)hvv);
                    oh[idx0 + (size_t)r * HD_] = hvv;
                    ol[idx0 + (size_t)r * HD_] = lvv;
                }
            }
        }
    }
    if constexpr (MODE == 1) {
        __syncthreads();
        bf16* tr = sm;
#pragma unroll
        for (int j = 0; j < JN; j++) {
            int nl = wc * (BN / 2) + j * 16 + lrow;
            float hv = hm[(n0 + nl) >> 7];
#pragma unroll
            for (int i = 0; i < IM; i++) {
                int ml = wr * (BM / 2) + i * 16 + quad * 4;
                bf16x4 pk;
#pragma unroll
                for (int r = 0; r < 4; r++) pk[r] = (bf16)(acc[i][j][r] * hv);
                *(bf16x4*)&tr[nl * 136 + ml] = pk;
            }
        }
        __syncthreads();
        const int bI = m0 >> 11;
        const int s0 = m0 & (S_ - 1);
#pragma unroll
        for (int w = 0; w < 8; w++) {
            int nrow = w * 16 + (t >> 4);
            int c = t & 15;
            bf16x8 vv = *(const bf16x8*)&tr[nrow * 136 + c * 8];
            int ng = n0 + nrow;
            int h = ng >> 7, hd = ng & 127;
            *(bf16x8*)&o_vt[((size_t)(bI * H_ + h) * HD_ + hd) * S_ + s0 + c * 8] = vv;
        }
    }
    if constexpr (MODE == 2) {
#pragma unroll
        for (int j = 0; j < JN; j++) {
            int n = n0 + wc * (BN / 2) + j * 16 + lrow;
#pragma unroll
            for (int i = 0; i < IM; i++) {
                int mB = m0 + wr * (BM / 2) + i * 16 + quad * 4;
#pragma unroll
                for (int r = 0; r < 4; r++)
                    o_f32[(size_t)(mB + r) * D_ + n] = acc[i][j][r];
            }
        }
    }
}

// =================== causal flash attention, QBLK=128, 8 waves ===================
// Structural change vs round-5: each block covers 128 q-rows (8 waves x 16 rows,
// per-wave code identical to proven 4-wave version). K/V tile-stages per bh drop
// 528 -> 272 (half the staging traffic + barriers). Staging split across 8 waves
// (same LDS image). Waves below the causal diagonal skip compute (wave-uniform).
#define SPLD 72

__global__ __launch_bounds__(512, 2)
void attn_kernel(const bf16* __restrict__ qh_, const bf16* __restrict__ ql_,
                 const bf16* __restrict__ kh_, const bf16* __restrict__ kl_,
                 const bf16* __restrict__ vt_, const float* __restrict__ am,
                 bf16* __restrict__ outp) {
    // 512 blocks: id = slot*8 + xcd; 4 bh per XCD; biggest q-blocks first
    const int id = blockIdx.x;
    const int xcd = id & 7, slot = id >> 3;       // slot 0..63
    const int bh = xcd * 4 + (slot & 3);
    const int qb = 15 - (slot >> 2);              // 16 q-blocks of 128 rows
    const int b = bh >> 4, h = bh & 15;
    const int i0 = qb * 128;
    const int t = threadIdx.x, wave = t >> 6, lane = t & 63;
    const int lrow = lane & 15, quad = lane >> 4;

    __shared__ bf16 skh[64 * 128];                // swizzled [j][d]
    __shared__ bf16 skl[64 * 128];
    __shared__ bf16 svt[128 * 64];                // swizzled [d][j]
    __shared__ bf16 sp[8][16 * SPLD];             // per-wave P strip
    __shared__ float samadd[S_];                  // (1-am)*-1e4 table

    const size_t kbase = (size_t)bh * S_ * HD_;
    const size_t vbase = (size_t)bh * HD_ * S_;

    // stage amadd table once (512 thr x 4 f32)
    {
        int j = t * 4;
        float4 a0 = *(const float4*)(am + b * S_ + j);
        float4 r0 = {(1.0f - a0.x) * -10000.0f, (1.0f - a0.y) * -10000.0f,
                     (1.0f - a0.z) * -10000.0f, (1.0f - a0.w) * -10000.0f};
        *(float4*)&samadd[j] = r0;
    }

    // Q fragments (hi+lo) straight to registers — per-wave 16 rows, as before
    const int qrow = i0 + wave * 16 + lrow;
    bf16x8 qhf[4], qlf[4];
#pragma unroll
    for (int c = 0; c < 4; c++) {
        qhf[c] = *(const bf16x8*)&qh_[kbase + (size_t)qrow * HD_ + c * 32 + quad * 8];
        qlf[c] = *(const bf16x8*)&ql_[kbase + (size_t)qrow * HD_ + c * 32 + quad * 8];
    }

    // prefetch registers (24 VGPRs): K hi 2, K lo 2, V 2 (split over 8 waves)
    u32x4 kpre[4], vpre[2];
    auto issueKV = [&](int j0) {
#pragma unroll
        for (int p = 0; p < 2; p++) {
            int rb = wave * 8 + p * 4;
            int r = rb + (lane >> 4);
            int gl = ((lane & 15) ^ (r & 7)) * 8;
            kpre[p]     = *(const u32x4*)(kh_ + kbase + (size_t)(j0 + r) * HD_ + gl);
            kpre[2 + p] = *(const u32x4*)(kl_ + kbase + (size_t)(j0 + r) * HD_ + gl);
        }
#pragma unroll
        for (int p = 0; p < 2; p++) {
            int db = wave * 16 + p * 8;
            int d = db + (lane >> 3);
            int gl = ((lane & 7) ^ (d & 7)) * 8;
            vpre[p] = *(const u32x4*)(vt_ + vbase + (size_t)d * S_ + j0 + gl);
        }
    };
    auto writeKV = [&]() {
#pragma unroll
        for (int p = 0; p < 2; p++) {
            int rb = wave * 8 + p * 4;
            *(u32x4*)&skh[rb * 128 + lane * 8] = kpre[p];
            *(u32x4*)&skl[rb * 128 + lane * 8] = kpre[2 + p];
        }
#pragma unroll
        for (int p = 0; p < 2; p++) {
            int db = wave * 16 + p * 8;
            *(u32x4*)&svt[db * 64 + lane * 8] = vpre[p];
        }
    };

    float m_i[4], l_i[4];
    f32x4 O[8];
#pragma unroll
    for (int r = 0; r < 4; r++) { m_i[r] = -INFINITY; l_i[r] = 0.f; }
#pragma unroll
    for (int n2 = 0; n2 < 8; n2++) O[n2] = (f32x4){0.f, 0.f, 0.f, 0.f};

    const float scale = 0.08838834764831845f;  // 1/sqrt(128)
    const int wbase = i0 + wave * 16;          // this wave's first q-row
    const int jmax = i0 + 64;                  // last tile start (rows to i0+127)

    issueKV(0);
    __syncthreads();                           // samadd visible

    for (int j0 = 0; j0 <= jmax; j0 += 64) {
        BAR();                                 // all waves done reading prev LDS
        writeKV();                             // reg deps -> counted vmcnt
        if (j0 + 64 <= jmax) issueKV(j0 + 64);
        asm volatile("s_waitcnt lgkmcnt(0)" ::: "memory");
        BAR();                                 // LDS tile visible to all

        // wave-uniform skip: tile entirely above causal diagonal for this wave
        if (j0 > wbase + 15) continue;

        float amadd[4];
#pragma unroll
        for (int nt = 0; nt < 4; nt++)
            amadd[nt] = samadd[j0 + nt * 16 + lrow];

        // QK^T: 16 rows x 64 cols, split 3-MFMA, swizzled B-frag reads
        f32x4 s4[4];
#pragma unroll
        for (int nt = 0; nt < 4; nt++) s4[nt] = (f32x4){0.f, 0.f, 0.f, 0.f};
        __builtin_amdgcn_s_setprio(1);
#pragma unroll
        for (int c = 0; c < 4; c++) {
#pragma unroll
            for (int nt = 0; nt < 4; nt++) {
                int ka = (nt * 16 + lrow) * 128 + (((c * 4 + quad) ^ (lrow & 7)) * 8);
                bf16x8 kb8 = *(const bf16x8*)&skh[ka];
                bf16x8 lb8 = *(const bf16x8*)&skl[ka];
                s4[nt] = mfma16(qhf[c], kb8, s4[nt]);
                s4[nt] = mfma16(qhf[c], lb8, s4[nt]);
                s4[nt] = mfma16(qlf[c], kb8, s4[nt]);
            }
        }
        __builtin_amdgcn_s_setprio(0);

        const bool needmask = (j0 + 63 > wbase);
#pragma unroll
        for (int r = 0; r < 4; r++) {
            const int rglob = wbase + quad * 4 + r;
            float sv[4], pw[4];
            float mx = -INFINITY;
#pragma unroll
            for (int nt = 0; nt < 4; nt++) {
                float xv = s4[nt][r] * scale + amadd[nt];
                if (needmask && (j0 + nt * 16 + lrow) > rglob) xv = -INFINITY;
                sv[nt] = xv;
                mx = fmaxf(mx, xv);
            }
#pragma unroll
            for (int off = 1; off < 16; off <<= 1) mx = fmaxf(mx, __shfl_xor(mx, off));
            float mnew = fmaxf(m_i[r], mx);
            float alpha = __expf(m_i[r] - mnew);
            float ps = 0.f;
#pragma unroll
            for (int nt = 0; nt < 4; nt++) { pw[nt] = __expf(sv[nt] - mnew); ps += pw[nt]; }
#pragma unroll
            for (int off = 1; off < 16; off <<= 1) ps += __shfl_xor(ps, off);
            l_i[r] = l_i[r] * alpha + ps;
            m_i[r] = mnew;
#pragma unroll
            for (int n2 = 0; n2 < 8; n2++) O[n2][r] *= alpha;
#pragma unroll
            for (int nt = 0; nt < 4; nt++)
                sp[wave][(quad * 4 + r) * SPLD + nt * 16 + lrow] = (bf16)pw[nt];
        }
        asm volatile("s_waitcnt lgkmcnt(0)" ::: "memory");   // sp per-wave

        // PV: O += P * V, swizzled V^T frag reads
        __builtin_amdgcn_s_setprio(1);
#pragma unroll
        for (int k2 = 0; k2 < 2; k2++) {
            bf16x8 pf = *(const bf16x8*)&sp[wave][lrow * SPLD + k2 * 32 + quad * 8];
            const int gp = ((quad + k2 * 4) ^ (lrow & 7)) * 8;
#pragma unroll
            for (int n2 = 0; n2 < 8; n2++) {
                bf16x8 vf8 = *(const bf16x8*)&svt[(n2 * 16 + lrow) * 64 + gp];
                O[n2] = mfma16(pf, vf8, O[n2]);
            }
        }
        __builtin_amdgcn_s_setprio(0);
    }

    float inv[4];
#pragma unroll
    for (int r = 0; r < 4; r++) inv[r] = 1.0f / l_i[r];
#pragma unroll
    for (int n2 = 0; n2 < 8; n2++)
#pragma unroll
        for (int r = 0; r < 4; r++) {
            int srow = i0 + wave * 16 + quad * 4 + r;
            outp[((size_t)(b * S_ + srow)) * D_ + h * HD_ + n2 * 16 + lrow] =
                (bf16)(O[n2][r] * inv[r]);
        }
}

// =================== launch ===================
extern "C" void kernel_launch(void* const* d_in, const int* in_sizes, int n_in,
                              void* d_out, int out_size, void* d_ws, size_t ws_size,
                              hipStream_t stream) {
    const float* x  = (const float*)d_in[0];
    const float* qm = (const float*)d_in[1];
    const float* km = (const float*)d_in[2];
    const float* vm = (const float*)d_in[3];
    const float* om = (const float*)d_in[4];
    const float* hm = (const float*)d_in[5];
    const float* am = (const float*)d_in[6];
    const float* sw = (const float*)d_in[7];
    float* out = (float*)d_out;

    const size_t P = (size_t)B_ * H_ * S_ * HD_ * sizeof(bf16);   // 16 MiB
    char* ws = (char*)d_ws;
    bf16* xh = (bf16*)(ws + 0 * P);
    bf16* xl = (bf16*)(ws + 1 * P);
    bf16* qh = (bf16*)(ws + 2 * P);
    bf16* ql = (bf16*)(ws + 3 * P);
    bf16* kh = (bf16*)(ws + 4 * P);
    bf16* kl = (bf16*)(ws + 5 * P);
    bf16* attn_out = xh;
    bf16* vmb = xl;
    bf16* omb = qh;
    bf16* vt  = (bf16*)d_out;
    bf16* qmb = (bf16*)((char*)d_out + 16u * 1024 * 1024);
    bf16* kmb = (bf16*)((char*)d_out + 24u * 1024 * 1024);

    precast_all<<<8192, 256, 0, stream>>>(x, xh, xl, qm, qmb, km, kmb, sw);

    // q/k projection: 256x128 tiles, virtual K=4096 (hi|lo), 512 blocks = 2/CU
    gemm2p<256, 128, 0><<<dim3(32, 16), 256, 0, stream>>>(
        xh, xl, qmb, kmb, hm, qh, ql, kh, kl, nullptr, nullptr, 128);

    // v projection (hi only): 128x128 tiles, 512 blocks; writes V^T directly
    precast_mask<<<2048, 256, 0, stream>>>(vm, vmb, sw);
    gemm2p<128, 128, 1><<<dim3(16, 32), 256, 0, stream>>>(
        xh, nullptr, vmb, nullptr, hm,
        nullptr, nullptr, nullptr, nullptr, vt, nullptr, 64);

    // attention: 512 blocks (16 qblk x 32 bh), QBLK=128, 8 waves
    attn_kernel<<<512, 512, 0, stream>>>(qh, ql, kh, kl, vt, am, attn_out);

    // output projection: 128x128 tiles, 512 blocks, f32 out
    precast_mask<<<2048, 256, 0, stream>>>(om, omb, sw);
    gemm2p<128, 128, 2><<<dim3(16, 32), 256, 0, stream>>>(
        attn_out, nullptr, omb, nullptr, hm,
        nullptr, nullptr, nullptr, nullptr, nullptr, out, 64);
}